// Round 8
// baseline (986.619 us; speedup 1.0000x reference)
//
#include <hip/hip_runtime.h>
#include <hip/hip_fp16.h>
#include <float.h>

#define M_ROWS 32768
#define E_DIM  512
#define N_E    8192

#define BM 128
#define BN 128
#define BK 32
#define NQ 4                    // quarters of the e-range
#define EQ (N_E / NQ)           // 2048 codes per quarter
#define SLOT_BYTES 16384        // A 8KB + B 8KB per K-step slot

typedef __attribute__((ext_vector_type(8))) _Float16 half8;
typedef __attribute__((ext_vector_type(4))) float f32x4;

__device__ inline void gl_lds16(const void* g, void* l) {
    __builtin_amdgcn_global_load_lds(
        (const __attribute__((address_space(1))) unsigned int*)g,
        (__attribute__((address_space(3))) unsigned int*)l, 16, 0, 0);
}

// ---------------- fp32 -> fp16 (RTNE) ----------------
__global__ __launch_bounds__(256) void f16_cast_kernel(const float* __restrict__ X,
                                                       ushort* __restrict__ H,
                                                       int n4) {
    int i = blockIdx.x * 256 + threadIdx.x;
    if (i >= n4) return;
    float4 v = ((const float4*)X)[i];
    float c[4] = {v.x, v.y, v.z, v.w};
    ushort hh[4];
    #pragma unroll
    for (int j = 0; j < 4; j++) {
        __half hb = __float2half(c[j]);
        hh[j] = *(ushort*)&hb;
    }
    ushort4 h = {hh[0], hh[1], hh[2], hh[3]};
    ((ushort4*)H)[i] = h;
}

// ---------------- wnorm[e] = sum_k W[e][k]^2 (fp32, exact) ----------------
__global__ __launch_bounds__(256) void wnorm_kernel(const float* __restrict__ W,
                                                    float* __restrict__ wnorm) {
    int wave_id = (int)((blockIdx.x * blockDim.x + threadIdx.x) >> 6);
    int lane = threadIdx.x & 63;
    if (wave_id >= N_E) return;
    const float* row = W + (size_t)wave_id * E_DIM;
    float4 v0 = *(const float4*)(row + lane * 4);
    float4 v1 = *(const float4*)(row + 256 + lane * 4);
    float s = v0.x*v0.x + v0.y*v0.y + v0.z*v0.z + v0.w*v0.w
            + v1.x*v1.x + v1.y*v1.y + v1.z*v1.z + v1.w*v1.w;
    #pragma unroll
    for (int off = 32; off; off >>= 1) s += __shfl_down(s, off);
    if (lane == 0) wnorm[wave_id] = s;
}

struct Top2 { float v0, v1; int i0, i1; };

__device__ inline Top2 merge2(Top2 A, Top2 B) {
    bool af = (A.v0 < B.v0) || (A.v0 == B.v0 && A.i0 < B.i0);
    float Wv1 = af ? A.v1 : B.v1; int Wi1 = af ? A.i1 : B.i1;
    float Lv0 = af ? B.v0 : A.v0; int Li0 = af ? B.i0 : A.i0;
    bool s2 = (Wv1 < Lv0) || (Wv1 == Lv0 && Wi1 < Li0);
    Top2 R;
    R.v0 = af ? A.v0 : B.v0; R.i0 = af ? A.i0 : B.i0;
    R.v1 = s2 ? Wv1 : Lv0;   R.i1 = s2 ? Wi1 : Li0;
    return R;
}

// ---------------- fp16 MFMA screen (K=512) + per-row top-2 per QUARTER ----------------
// Screen semantics identical to the PASSING R4/R6/R7 config. Execution change:
// LDS-BW was the R7 bottleneck (~37KB/block-step ~= dur). Wave tile 64x64 (4x4
// fragments) + block 128x128 halves LDS bytes/FLOP (reads (M+N)/(M*N): 0.046->
// 0.031; staged: 0.023->0.016). Same R7 4-deep slot pipeline, counted vmcnt
// (4 loads/stage -> vmcnt 8/8/4/0), one barrier per K-step. launch_bounds(256,2)
// = 2 waves/SIMD -> 256-VGPR budget for ~185 live regs, 2 blocks/CU by LDS.
__global__ __launch_bounds__(256, 2) void argmin_mfma(
        const ushort* __restrict__ Zh, const ushort* __restrict__ Wh,
        const float* __restrict__ wnorm, int* __restrict__ cand) {
    __shared__ __align__(16) char Lds[4][SLOT_BYTES];   // 64 KB
    __shared__ float4 SmTop[BM][2];                     // 4 KB

    const int t = threadIdx.x;
    const int lane = t & 63;
    const int wid = t >> 6;            // 0..3
    const int wave_m = wid >> 1;       // 0..1 (64-row chunk)
    const int wave_n = wid & 1;        // 0..1 (64-col chunk)
    const int l15 = lane & 15, l4 = lane >> 4;

    // chunked XCD remap (1024 blocks, 8 XCDs, 128-block chunks; bijective).
    const int id = blockIdx.x;
    const int orig = (id & 7) * 128 + (id >> 3);
    const int quarter = orig >> 8;
    const int rowblk = orig & 255;
    const int row0 = rowblk * BM;
    const int ebase = quarter * EQ;

    // staging: A 128x32 = 512 16B-chunks (2/thread), B same (2/thread).
    // Swizzle on the GLOBAL side (LDS dest linear, rule #21): k-chunk ^= (row>>1)&3.
    // Rows srow and srow+64 share (row>>1)&3, so one akc serves all four loads.
    const int srow = t >> 2;                                    // 0..63
    const int akc = ((t & 3) ^ ((srow >> 1) & 3)) * 8;          // elements
    const ushort* AbaseS0 = Zh + (size_t)(row0 + srow) * E_DIM + akc;
    const ushort* AbaseS1 = AbaseS0 + (size_t)64 * E_DIM;
    const ushort* BbaseS0 = Wh + (size_t)(ebase + srow) * E_DIM + akc;
    const ushort* BbaseS1 = BbaseS0 + (size_t)64 * E_DIM;

    // fragment read offsets (same involution), bytes within a slot
    const int kchunk_b = (l4 ^ ((l15 >> 1) & 3)) * 16;
    const int a_roff = (wave_m * 64 + l15) * 64 + kchunk_b;          // A at slot+0
    const int b_roff = 8192 + (wave_n * 64 + l15) * 64 + kchunk_b;   // B at slot+8K

    // per-thread top2 over 16 row-slots q=mi*4+r; row = wave_m*64+mi*16+l4*4+r
    float v0[16], v1[16];
    int i0[16], i1[16];
    #pragma unroll
    for (int q = 0; q < 16; q++) { v0[q] = FLT_MAX; v1[q] = FLT_MAX; i0[q] = 0; i1[q] = 0; }

    f32x4 acc[4][4];
    #pragma unroll
    for (int mi = 0; mi < 4; mi++)
        #pragma unroll
        for (int ni = 0; ni < 4; ni++)
            acc[mi][ni] = (f32x4){0.f, 0.f, 0.f, 0.f};

    // step s in [0,256): e0-tile = s>>4 (128 codes), k-step = s&15
    #define STAGE(s) do {                                                        \
        int _s = (s);                                                            \
        char* _sl = Lds[_s & 3];                                                 \
        size_t ko = (size_t)(_s & 15) * BK;                                      \
        size_t eo = ((size_t)(_s >> 4) << 16);  /* 128 rows * 512 elems */       \
        gl_lds16(AbaseS0 + ko, _sl + t * 16);                                    \
        gl_lds16(AbaseS1 + ko, _sl + 4096 + t * 16);                             \
        gl_lds16(BbaseS0 + eo + ko, _sl + 8192 + t * 16);                        \
        gl_lds16(BbaseS1 + eo + ko, _sl + 12288 + t * 16);                       \
    } while (0)

    #define FOLD(E0) do {                                                        \
        _Pragma("unroll")                                                        \
        for (int ni = 0; ni < 4; ni++) {                                         \
            int col = ebase + (E0) * BN + wave_n * 64 + ni * 16 + l15;           \
            float wn = wnorm[col];                                               \
            _Pragma("unroll")                                                    \
            for (int mi = 0; mi < 4; mi++)                                       \
                _Pragma("unroll")                                                \
                for (int r = 0; r < 4; r++) {                                    \
                    float sc = fmaf(-2.0f, acc[mi][ni][r], wn);                  \
                    int q = mi * 4 + r;                                          \
                    if (sc < v0[q])      { v1[q] = v0[q]; i1[q] = i0[q]; v0[q] = sc; i0[q] = col; } \
                    else if (sc < v1[q]) { v1[q] = sc; i1[q] = col; }            \
                }                                                                \
        }                                                                        \
        _Pragma("unroll")                                                        \
        for (int mi = 0; mi < 4; mi++)                                           \
            _Pragma("unroll")                                                    \
            for (int ni = 0; ni < 4; ni++)                                       \
                acc[mi][ni] = (f32x4){0.f, 0.f, 0.f, 0.f};                       \
    } while (0)

    #define STEP(i, VMSTR, DO_STAGE) do {                                        \
        asm volatile("s_waitcnt " VMSTR ::: "memory");                           \
        __builtin_amdgcn_s_barrier();                                            \
        __builtin_amdgcn_sched_barrier(0);                                       \
        if (DO_STAGE) STAGE((i) + 3);                                            \
        const char* _sl = Lds[(i) & 3];                                          \
        half8 a_[4], b_[4];                                                      \
        _Pragma("unroll")                                                        \
        for (int mi = 0; mi < 4; mi++) a_[mi] = *(const half8*)(_sl + a_roff + mi * 1024); \
        _Pragma("unroll")                                                        \
        for (int ni = 0; ni < 4; ni++) b_[ni] = *(const half8*)(_sl + b_roff + ni * 1024); \
        __builtin_amdgcn_s_setprio(1);                                           \
        _Pragma("unroll")                                                        \
        for (int mi = 0; mi < 4; mi++)                                           \
            _Pragma("unroll")                                                    \
            for (int ni = 0; ni < 4; ni++)                                       \
                acc[mi][ni] = __builtin_amdgcn_mfma_f32_16x16x32_f16(a_[mi], b_[ni], acc[mi][ni], 0, 0, 0); \
        __builtin_amdgcn_s_setprio(0);                                           \
        if (((i) & 15) == 15) FOLD((i) >> 4);                                    \
    } while (0)

    STAGE(0); STAGE(1); STAGE(2);
    for (int i = 0; i < 253; ++i) STEP(i, "vmcnt(8)", true);
    STEP(253, "vmcnt(8)", false);
    STEP(254, "vmcnt(4)", false);
    STEP(255, "vmcnt(0)", false);

    // 16-lane top2 butterfly (lanes sharing a row), then cross-wave_n merge via LDS
    #pragma unroll
    for (int mi = 0; mi < 4; mi++)
        #pragma unroll
        for (int r = 0; r < 4; r++) {
            int q = mi * 4 + r;
            Top2 T = {v0[q], v1[q], i0[q], i1[q]};
            #pragma unroll
            for (int mk = 1; mk <= 8; mk <<= 1) {
                Top2 O;
                O.v0 = __shfl_xor(T.v0, mk); O.v1 = __shfl_xor(T.v1, mk);
                O.i0 = __shfl_xor(T.i0, mk); O.i1 = __shfl_xor(T.i1, mk);
                T = merge2(T, O);
            }
            if (l15 == 0) {
                int rl = wave_m * 64 + mi * 16 + l4 * 4 + r;
                SmTop[rl][wave_n] = make_float4(T.v0, __int_as_float(T.i0), T.v1, __int_as_float(T.i1));
            }
        }
    __syncthreads();
    if (t < BM) {
        float4 Fa = SmTop[t][0], Fb = SmTop[t][1];
        Top2 A2 = {Fa.x, Fa.z, __float_as_int(Fa.y), __float_as_int(Fa.w)};
        Top2 B2 = {Fb.x, Fb.z, __float_as_int(Fb.y), __float_as_int(Fb.w)};
        Top2 T = merge2(A2, B2);
        cand[(size_t)(row0 + t) * (2 * NQ) + quarter * 2 + 0] = T.i0;
        cand[(size_t)(row0 + t) * (2 * NQ) + quarter * 2 + 1] = T.i1;
    }
    #undef STAGE
    #undef FOLD
    #undef STEP
}

// ---------------- fp32 rescore of 8 candidates + gather z_q + loss partial ----------------
__global__ __launch_bounds__(256) void rescore_gather_loss(
        const float* __restrict__ Z, const float* __restrict__ W,
        const float* __restrict__ wnorm, const int* __restrict__ cand,
        float* __restrict__ out, float* __restrict__ partials) {
    const int n = blockIdx.x;
    const int t = threadIdx.x;
    const int lane = t & 63, wv = t >> 6;
    int c[8];
    #pragma unroll
    for (int j = 0; j < 8; j++) c[j] = cand[(size_t)n * 8 + j];
    float2 zv = ((const float2*)(Z + (size_t)n * E_DIM))[t];
    float2 wvv[8];
    #pragma unroll
    for (int j = 0; j < 8; j++)
        wvv[j] = ((const float2*)(W + (size_t)c[j] * E_DIM))[t];
    __shared__ float red[4][8];
    #pragma unroll
    for (int j = 0; j < 8; j++) {
        float s = zv.x * wvv[j].x + zv.y * wvv[j].y;
        #pragma unroll
        for (int off = 32; off; off >>= 1) s += __shfl_down(s, off);
        if (lane == 0) red[wv][j] = s;
    }
    __syncthreads();
    float best = FLT_MAX; int bj = 0, bc = 0x7fffffff;
    #pragma unroll
    for (int j = 0; j < 8; j++) {
        float d = red[0][j] + red[1][j] + red[2][j] + red[3][j];
        float s = wnorm[c[j]] - 2.0f * d;
        if (s < best || (s == best && c[j] < bc)) { best = s; bj = j; bc = c[j]; }
    }
    float2 wq = wvv[0];                 // static-index select (rule #20)
    #pragma unroll
    for (int j = 1; j < 8; j++) if (bj == j) wq = wvv[j];
    ((float2*)(out + 1 + (size_t)n * E_DIM))[t] = wq;   // z_q_st == z_q numerically
    float d0 = wq.x - zv.x, d1 = wq.y - zv.y;
    float sl = d0 * d0 + d1 * d1;
    #pragma unroll
    for (int off = 32; off; off >>= 1) sl += __shfl_down(sl, off);
    __shared__ float red2[4];
    if (lane == 0) red2[wv] = sl;
    __syncthreads();
    if (t == 0) {
        partials[n] = red2[0] + red2[1] + red2[2] + red2[3];
        out[1 + (size_t)M_ROWS * E_DIM + n] = (float)bc;
    }
}

// ---------------- deterministic final loss reduction ----------------
__global__ __launch_bounds__(256) void loss_reduce_kernel(const float* __restrict__ partials,
                                                          float* __restrict__ out) {
    const int t = threadIdx.x;
    float s = 0.0f;
    for (int i = t; i < M_ROWS; i += 256) s += partials[i];
    #pragma unroll
    for (int off = 32; off; off >>= 1) s += __shfl_down(s, off);
    __shared__ float red[4];
    if ((t & 63) == 0) red[t >> 6] = s;
    __syncthreads();
    if (t == 0) {
        float total = red[0] + red[1] + red[2] + red[3];
        out[0] = 2.0f * total / ((float)M_ROWS * (float)E_DIM);  // beta=1 collapses
    }
}

extern "C" void kernel_launch(void* const* d_in, const int* in_sizes, int n_in,
                              void* d_out, int out_size, void* d_ws, size_t ws_size,
                              hipStream_t stream) {
    const float* Z = (const float*)d_in[0];
    const float* W = (const float*)d_in[1];
    float* out = (float*)d_out;

    char* p = (char*)d_ws;
    ushort* Zh = (ushort*)p;      p += (size_t)M_ROWS * E_DIM * 2;
    ushort* Wh = (ushort*)p;      p += (size_t)N_E * E_DIM * 2;
    float* wnorm = (float*)p;     p += (size_t)N_E * 4;
    int* cand = (int*)p;          p += (size_t)M_ROWS * 8 * 4;
    float* partials = (float*)p;  p += (size_t)M_ROWS * 4;

    f16_cast_kernel<<<(M_ROWS * E_DIM / 4 + 255) / 256, 256, 0, stream>>>(Z, Zh, M_ROWS * E_DIM / 4);
    f16_cast_kernel<<<(N_E * E_DIM / 4 + 255) / 256, 256, 0, stream>>>(W, Wh, N_E * E_DIM / 4);
    wnorm_kernel<<<N_E / 4, 256, 0, stream>>>(W, wnorm);
    argmin_mfma<<<NQ * (M_ROWS / BM), 256, 0, stream>>>(Zh, Wh, wnorm, cand);
    rescore_gather_loss<<<M_ROWS, 256, 0, stream>>>(Z, W, wnorm, cand, out, partials);
    loss_reduce_kernel<<<1, 256, 0, stream>>>(partials, out);
}

// Round 10
// 748.203 us; speedup vs baseline: 1.3187x; 1.3187x over previous
//
#include <hip/hip_runtime.h>
#include <hip/hip_fp16.h>
#include <float.h>

#define M_ROWS 32768
#define E_DIM  512
#define N_E    8192

#define BM 64
#define BN 128
#define BK 32
#define NQ 4                    // quarters of the e-range
#define EQ (N_E / NQ)           // 2048 codes per quarter
#define SLOT_BYTES 12288        // A 4KB + B 8KB per K-step slot

typedef __attribute__((ext_vector_type(8))) _Float16 half8;
typedef __attribute__((ext_vector_type(4))) float f32x4;

// offset arg ALWAYS 0 (m97-proven semantics; R9 showed the imm-offset arg is
// NOT a plain global-address add on gfx950). Constant k-offsets are folded
// into the pointer operand instead.
__device__ __forceinline__ void gl_lds16(const void* g, void* l) {
    __builtin_amdgcn_global_load_lds(
        (const __attribute__((address_space(1))) unsigned int*)g,
        (__attribute__((address_space(3))) unsigned int*)l, 16, 0, 0);
}

// ---------------- fp32 -> fp16 (RTNE) ----------------
__global__ __launch_bounds__(256) void f16_cast_kernel(const float* __restrict__ X,
                                                       ushort* __restrict__ H,
                                                       int n4) {
    int i = blockIdx.x * 256 + threadIdx.x;
    if (i >= n4) return;
    float4 v = ((const float4*)X)[i];
    float c[4] = {v.x, v.y, v.z, v.w};
    ushort hh[4];
    #pragma unroll
    for (int j = 0; j < 4; j++) {
        __half hb = __float2half(c[j]);
        hh[j] = *(ushort*)&hb;
    }
    ushort4 h = {hh[0], hh[1], hh[2], hh[3]};
    ((ushort4*)H)[i] = h;
}

// ---------------- wnorm[e] = sum_k W[e][k]^2 (fp32, exact) ----------------
__global__ __launch_bounds__(256) void wnorm_kernel(const float* __restrict__ W,
                                                    float* __restrict__ wnorm) {
    int wave_id = (int)((blockIdx.x * blockDim.x + threadIdx.x) >> 6);
    int lane = threadIdx.x & 63;
    if (wave_id >= N_E) return;
    const float* row = W + (size_t)wave_id * E_DIM;
    float4 v0 = *(const float4*)(row + lane * 4);
    float4 v1 = *(const float4*)(row + 256 + lane * 4);
    float s = v0.x*v0.x + v0.y*v0.y + v0.z*v0.z + v0.w*v0.w
            + v1.x*v1.x + v1.y*v1.y + v1.z*v1.z + v1.w*v1.w;
    #pragma unroll
    for (int off = 32; off; off >>= 1) s += __shfl_down(s, off);
    if (lane == 0) wnorm[wave_id] = s;
}

struct Top2 { float v0, v1; int i0, i1; };

__device__ inline Top2 merge2(Top2 A, Top2 B) {
    bool af = (A.v0 < B.v0) || (A.v0 == B.v0 && A.i0 < B.i0);
    float Wv1 = af ? A.v1 : B.v1; int Wi1 = af ? A.i1 : B.i1;
    float Lv0 = af ? B.v0 : A.v0; int Li0 = af ? B.i0 : A.i0;
    bool s2 = (Wv1 < Lv0) || (Wv1 == Lv0 && Wi1 < Li0);
    Top2 R;
    R.v0 = af ? A.v0 : B.v0; R.i0 = af ? A.i0 : B.i0;
    R.v1 = s2 ? Wv1 : Lv0;   R.i1 = s2 ? Wi1 : Li0;
    return R;
}

// ---------------- fp16 MFMA screen (K=512) + per-row top-2 per QUARTER ----------------
// Geometry/pipeline semantics IDENTICAL to the passing R7 kernel (BM=64,BN=128,
// 4-wave 32x64 tiles, 4-slot counted-vmcnt pipeline, 3 blocks/CU). vs R9: the
// k-step constant goes into the POINTER (folded to the global offset: field by
// LLVM), offset arg = 0. All LDS addressing static (slot*12288 + frag*1024 imm).
// wnorm prefetched into registers per e0-tile so FOLD doesn't drain vmcnt(0).
__global__ __launch_bounds__(256, 2) void argmin_mfma(
        const ushort* __restrict__ Zh, const ushort* __restrict__ Wh,
        const float* __restrict__ wnorm, int* __restrict__ cand) {
    __shared__ __align__(16) char Lds[4 * SLOT_BYTES];  // 48 KB
    __shared__ float4 SmTop[BM][2];                     // 2 KB

    const int t = threadIdx.x;
    const int lane = t & 63;
    const int wid = t >> 6;            // 0..3
    const int wave_m = wid >> 1;       // 0..1 (32-row chunk)
    const int wave_n = wid & 1;        // 0..1 (64-col chunk)
    const int l15 = lane & 15, l4 = lane >> 4;

    // chunked XCD remap (2048 blocks, 8 XCDs, 256-block chunks; bijective)
    const int id = blockIdx.x;
    const int orig = (id & 7) * 256 + (id >> 3);
    const int quarter = orig >> 9;
    const int rowblk = orig & 511;
    const int row0 = rowblk * BM;
    const int ebase = quarter * EQ;

    // staging bases; swizzle on the GLOBAL side (LDS dest linear, rule #21):
    // k-chunk ^= (row>>1)&3. Rows srow and 64+srow share the xor (64%4==0).
    const int srow = t >> 2;
    const int akc = ((t & 3) ^ ((srow >> 1) & 3)) * 8;
    const ushort* Abase = Zh + (size_t)(row0 + srow) * E_DIM + akc;
    const ushort* Bc0 = Wh + (size_t)(ebase + srow) * E_DIM + akc;   // cur tile, rows 0-63
    const ushort* Bc1 = Bc0 + (size_t)64 * E_DIM;                    // cur tile, rows 64-127
    const ushort* Bn0 = Bc0 + (size_t)BN * E_DIM;                    // next tile
    const ushort* Bn1 = Bc1 + (size_t)BN * E_DIM;

    char* const ldsW = Lds + t * 16;   // stage dest (slot 0); + slot*12288 static

    // fragment read bases (same involution as staging), within slot 0
    const int kchunk_b = (l4 ^ ((l15 >> 1) & 3)) * 16;
    const char* const ldsA = Lds + (wave_m * 32 + l15) * 64 + kchunk_b;
    const char* const ldsB = Lds + 4096 + (wave_n * 64 + l15) * 64 + kchunk_b;

    // per-e0 wnorm prefetch base (4 per-lane values, stride 16 floats)
    const float* wn_ptr = wnorm + ebase + wave_n * 64 + l15;

    // per-thread top2 over 8 row-slots q=mi*4+r; row = wave_m*32+mi*16+l4*4+r
    float v0[8], v1[8];
    int i0[8], i1[8];
    #pragma unroll
    for (int q = 0; q < 8; q++) { v0[q] = FLT_MAX; v1[q] = FLT_MAX; i0[q] = 0; i1[q] = 0; }

    f32x4 acc[2][4];
    #pragma unroll
    for (int mi = 0; mi < 2; mi++)
        #pragma unroll
        for (int ni = 0; ni < 4; ni++)
            acc[mi][ni] = (f32x4){0.f, 0.f, 0.f, 0.f};

    // STG(P): stage k-step (P+3)&15 of the selected B tile into slot (P+3)&3.
    // Constant element offset folded into the pointer (offset arg stays 0).
    #define STG(P_, B0_, B1_) do {                                               \
        constexpr int _ss = (((P_) + 3) & 3) * SLOT_BYTES;                       \
        constexpr int _ke = (((P_) + 3) & 15) * BK;   /* elements = 64B/step */  \
        gl_lds16(Abase + _ke, ldsW + _ss);                                       \
        gl_lds16((B0_) + _ke, ldsW + _ss + 4096);                                \
        gl_lds16((B1_) + _ke, ldsW + _ss + 8192);                                \
    } while (0)

    #define BODY(P_, VMSTR, DOSTG, USENEXT) do {                                 \
        asm volatile("s_waitcnt " VMSTR ::: "memory");                           \
        __builtin_amdgcn_s_barrier();                                            \
        __builtin_amdgcn_sched_barrier(0);                                       \
        if (DOSTG) { if (USENEXT) STG(P_, Bn0, Bn1); else STG(P_, Bc0, Bc1); }   \
        {                                                                        \
            constexpr int _rs = ((P_) & 3) * SLOT_BYTES;                         \
            const char* _sa = ldsA + _rs;                                        \
            const char* _sb = ldsB + _rs;                                        \
            half8 a0_ = *(const half8*)(_sa);                                    \
            half8 a1_ = *(const half8*)(_sa + 1024);                             \
            half8 b0_ = *(const half8*)(_sb);                                    \
            half8 b1_ = *(const half8*)(_sb + 1024);                             \
            half8 b2_ = *(const half8*)(_sb + 2048);                             \
            half8 b3_ = *(const half8*)(_sb + 3072);                             \
            __builtin_amdgcn_s_setprio(1);                                       \
            acc[0][0] = __builtin_amdgcn_mfma_f32_16x16x32_f16(a0_, b0_, acc[0][0], 0, 0, 0); \
            acc[0][1] = __builtin_amdgcn_mfma_f32_16x16x32_f16(a0_, b1_, acc[0][1], 0, 0, 0); \
            acc[0][2] = __builtin_amdgcn_mfma_f32_16x16x32_f16(a0_, b2_, acc[0][2], 0, 0, 0); \
            acc[0][3] = __builtin_amdgcn_mfma_f32_16x16x32_f16(a0_, b3_, acc[0][3], 0, 0, 0); \
            acc[1][0] = __builtin_amdgcn_mfma_f32_16x16x32_f16(a1_, b0_, acc[1][0], 0, 0, 0); \
            acc[1][1] = __builtin_amdgcn_mfma_f32_16x16x32_f16(a1_, b1_, acc[1][1], 0, 0, 0); \
            acc[1][2] = __builtin_amdgcn_mfma_f32_16x16x32_f16(a1_, b2_, acc[1][2], 0, 0, 0); \
            acc[1][3] = __builtin_amdgcn_mfma_f32_16x16x32_f16(a1_, b3_, acc[1][3], 0, 0, 0); \
            __builtin_amdgcn_s_setprio(0);                                       \
        }                                                                        \
    } while (0)

    #define FOLD(E0) do {                                                        \
        _Pragma("unroll")                                                        \
        for (int ni = 0; ni < 4; ni++) {                                         \
            int col = ebase + (E0) * BN + wave_n * 64 + ni * 16 + l15;           \
            float wn = wn_pref[ni];                                              \
            _Pragma("unroll")                                                    \
            for (int mi = 0; mi < 2; mi++)                                       \
                _Pragma("unroll")                                                \
                for (int r = 0; r < 4; r++) {                                    \
                    float sc = fmaf(-2.0f, acc[mi][ni][r], wn);                  \
                    int q = mi * 4 + r;                                          \
                    if (sc < v0[q])      { v1[q] = v0[q]; i1[q] = i0[q]; v0[q] = sc; i0[q] = col; } \
                    else if (sc < v1[q]) { v1[q] = sc; i1[q] = col; }            \
                }                                                                \
        }                                                                        \
        _Pragma("unroll")                                                        \
        for (int mi = 0; mi < 2; mi++)                                           \
            _Pragma("unroll")                                                    \
            for (int ni = 0; ni < 4; ni++)                                       \
                acc[mi][ni] = (f32x4){0.f, 0.f, 0.f, 0.f};                       \
    } while (0)

    // prologue: stage ks 0..2 of tile 0 into slots 0..2
    STG(13, Bc0, Bc1); STG(14, Bc0, Bc1); STG(15, Bc0, Bc1);

    for (int e0 = 0; e0 < 16; ++e0) {
        float wn_pref[4];
        #pragma unroll
        for (int ni = 0; ni < 4; ni++) wn_pref[ni] = wn_ptr[ni * 16];

        BODY(0,  "vmcnt(6)", 1, 0);
        BODY(1,  "vmcnt(6)", 1, 0);
        BODY(2,  "vmcnt(6)", 1, 0);
        BODY(3,  "vmcnt(6)", 1, 0);
        BODY(4,  "vmcnt(6)", 1, 0);
        BODY(5,  "vmcnt(6)", 1, 0);
        BODY(6,  "vmcnt(6)", 1, 0);
        BODY(7,  "vmcnt(6)", 1, 0);
        BODY(8,  "vmcnt(6)", 1, 0);
        BODY(9,  "vmcnt(6)", 1, 0);
        BODY(10, "vmcnt(6)", 1, 0);
        BODY(11, "vmcnt(6)", 1, 0);
        BODY(12, "vmcnt(6)", 1, 0);
        if (e0 < 15) {
            // stage ks 0..2 of NEXT tile
            BODY(13, "vmcnt(6)", 1, 1);
            BODY(14, "vmcnt(6)", 1, 1);
            BODY(15, "vmcnt(6)", 1, 1);
        } else {
            BODY(13, "vmcnt(6)", 0, 0);
            BODY(14, "vmcnt(3)", 0, 0);
            BODY(15, "vmcnt(0)", 0, 0);
        }
        FOLD(e0);
        wn_ptr += BN;
        Bc0 += (size_t)BN * E_DIM; Bc1 += (size_t)BN * E_DIM;
        Bn0 += (size_t)BN * E_DIM; Bn1 += (size_t)BN * E_DIM;
    }

    // 16-lane top2 butterfly (lanes sharing a row), then cross-wave_n merge via LDS
    #pragma unroll
    for (int mi = 0; mi < 2; mi++)
        #pragma unroll
        for (int r = 0; r < 4; r++) {
            int q = mi * 4 + r;
            Top2 T = {v0[q], v1[q], i0[q], i1[q]};
            #pragma unroll
            for (int mk = 1; mk <= 8; mk <<= 1) {
                Top2 O;
                O.v0 = __shfl_xor(T.v0, mk); O.v1 = __shfl_xor(T.v1, mk);
                O.i0 = __shfl_xor(T.i0, mk); O.i1 = __shfl_xor(T.i1, mk);
                T = merge2(T, O);
            }
            if (l15 == 0) {
                int rl = wave_m * 32 + mi * 16 + l4 * 4 + r;
                SmTop[rl][wave_n] = make_float4(T.v0, __int_as_float(T.i0), T.v1, __int_as_float(T.i1));
            }
        }
    __syncthreads();
    if (t < BM) {
        float4 Fa = SmTop[t][0], Fb = SmTop[t][1];
        Top2 A2 = {Fa.x, Fa.z, __float_as_int(Fa.y), __float_as_int(Fa.w)};
        Top2 B2 = {Fb.x, Fb.z, __float_as_int(Fb.y), __float_as_int(Fb.w)};
        Top2 T = merge2(A2, B2);
        cand[(size_t)(row0 + t) * (2 * NQ) + quarter * 2 + 0] = T.i0;
        cand[(size_t)(row0 + t) * (2 * NQ) + quarter * 2 + 1] = T.i1;
    }
    #undef STG
    #undef BODY
    #undef FOLD
}

// ---------------- fp32 rescore of 8 candidates + gather z_q + loss partial ----------------
__global__ __launch_bounds__(256) void rescore_gather_loss(
        const float* __restrict__ Z, const float* __restrict__ W,
        const float* __restrict__ wnorm, const int* __restrict__ cand,
        float* __restrict__ out, float* __restrict__ partials) {
    const int n = blockIdx.x;
    const int t = threadIdx.x;
    const int lane = t & 63, wv = t >> 6;
    int c[8];
    #pragma unroll
    for (int j = 0; j < 8; j++) c[j] = cand[(size_t)n * 8 + j];
    float2 zv = ((const float2*)(Z + (size_t)n * E_DIM))[t];
    float2 wvv[8];
    #pragma unroll
    for (int j = 0; j < 8; j++)
        wvv[j] = ((const float2*)(W + (size_t)c[j] * E_DIM))[t];
    __shared__ float red[4][8];
    #pragma unroll
    for (int j = 0; j < 8; j++) {
        float s = zv.x * wvv[j].x + zv.y * wvv[j].y;
        #pragma unroll
        for (int off = 32; off; off >>= 1) s += __shfl_down(s, off);
        if (lane == 0) red[wv][j] = s;
    }
    __syncthreads();
    float best = FLT_MAX; int bj = 0, bc = 0x7fffffff;
    #pragma unroll
    for (int j = 0; j < 8; j++) {
        float d = red[0][j] + red[1][j] + red[2][j] + red[3][j];
        float s = wnorm[c[j]] - 2.0f * d;
        if (s < best || (s == best && c[j] < bc)) { best = s; bj = j; bc = c[j]; }
    }
    float2 wq = wvv[0];                 // static-index select (rule #20)
    #pragma unroll
    for (int j = 1; j < 8; j++) if (bj == j) wq = wvv[j];
    ((float2*)(out + 1 + (size_t)n * E_DIM))[t] = wq;   // z_q_st == z_q numerically
    float d0 = wq.x - zv.x, d1 = wq.y - zv.y;
    float sl = d0 * d0 + d1 * d1;
    #pragma unroll
    for (int off = 32; off; off >>= 1) sl += __shfl_down(sl, off);
    __shared__ float red2[4];
    if (lane == 0) red2[wv] = sl;
    __syncthreads();
    if (t == 0) {
        partials[n] = red2[0] + red2[1] + red2[2] + red2[3];
        out[1 + (size_t)M_ROWS * E_DIM + n] = (float)bc;
    }
}

// ---------------- deterministic final loss reduction ----------------
__global__ __launch_bounds__(256) void loss_reduce_kernel(const float* __restrict__ partials,
                                                          float* __restrict__ out) {
    const int t = threadIdx.x;
    float s = 0.0f;
    for (int i = t; i < M_ROWS; i += 256) s += partials[i];
    #pragma unroll
    for (int off = 32; off; off >>= 1) s += __shfl_down(s, off);
    __shared__ float red[4];
    if ((t & 63) == 0) red[t >> 6] = s;
    __syncthreads();
    if (t == 0) {
        float total = red[0] + red[1] + red[2] + red[3];
        out[0] = 2.0f * total / ((float)M_ROWS * (float)E_DIM);  // beta=1 collapses
    }
}

extern "C" void kernel_launch(void* const* d_in, const int* in_sizes, int n_in,
                              void* d_out, int out_size, void* d_ws, size_t ws_size,
                              hipStream_t stream) {
    const float* Z = (const float*)d_in[0];
    const float* W = (const float*)d_in[1];
    float* out = (float*)d_out;

    char* p = (char*)d_ws;
    ushort* Zh = (ushort*)p;      p += (size_t)M_ROWS * E_DIM * 2;
    ushort* Wh = (ushort*)p;      p += (size_t)N_E * E_DIM * 2;
    float* wnorm = (float*)p;     p += (size_t)N_E * 4;
    int* cand = (int*)p;          p += (size_t)M_ROWS * 8 * 4;
    float* partials = (float*)p;  p += (size_t)M_ROWS * 4;

    f16_cast_kernel<<<(M_ROWS * E_DIM / 4 + 255) / 256, 256, 0, stream>>>(Z, Zh, M_ROWS * E_DIM / 4);
    f16_cast_kernel<<<(N_E * E_DIM / 4 + 255) / 256, 256, 0, stream>>>(W, Wh, N_E * E_DIM / 4);
    wnorm_kernel<<<N_E / 4, 256, 0, stream>>>(W, wnorm);
    argmin_mfma<<<NQ * (M_ROWS / BM), 256, 0, stream>>>(Zh, Wh, wnorm, cand);
    rescore_gather_loss<<<M_ROWS, 256, 0, stream>>>(Z, W, wnorm, cand, out, partials);
    loss_reduce_kernel<<<1, 256, 0, stream>>>(partials, out);
}

// Round 11
// 734.234 us; speedup vs baseline: 1.3437x; 1.0190x over previous
//
#include <hip/hip_runtime.h>
#include <hip/hip_fp16.h>
#include <float.h>

#define M_ROWS 32768
#define E_DIM  512
#define N_E    8192

#define BM 32
#define BN 128
#define BK 32
#define NQ 4                    // quarters of the e-range
#define EQ (N_E / NQ)           // 2048 codes per quarter

typedef __attribute__((ext_vector_type(8))) _Float16 half8;
typedef __attribute__((ext_vector_type(4))) float f32x4;

// offset arg ALWAYS 0 (m97-proven semantics; R9 showed the imm-offset arg is
// NOT a plain global-address add on gfx950). Constant offsets are folded into
// the pointer operand.
__device__ __forceinline__ void gl_lds16(const void* g, void* l) {
    __builtin_amdgcn_global_load_lds(
        (const __attribute__((address_space(1))) unsigned int*)g,
        (__attribute__((address_space(3))) unsigned int*)l, 16, 0, 0);
}

// ---------------- fp32 -> fp16 (RTNE) ----------------
__global__ __launch_bounds__(256) void f16_cast_kernel(const float* __restrict__ X,
                                                       ushort* __restrict__ H,
                                                       int n4) {
    int i = blockIdx.x * 256 + threadIdx.x;
    if (i >= n4) return;
    float4 v = ((const float4*)X)[i];
    float c[4] = {v.x, v.y, v.z, v.w};
    ushort hh[4];
    #pragma unroll
    for (int j = 0; j < 4; j++) {
        __half hb = __float2half(c[j]);
        hh[j] = *(ushort*)&hb;
    }
    ushort4 h = {hh[0], hh[1], hh[2], hh[3]};
    ((ushort4*)H)[i] = h;
}

// ---------------- wnorm[e] = sum_k W[e][k]^2 (fp32, exact) ----------------
__global__ __launch_bounds__(256) void wnorm_kernel(const float* __restrict__ W,
                                                    float* __restrict__ wnorm) {
    int wave_id = (int)((blockIdx.x * blockDim.x + threadIdx.x) >> 6);
    int lane = threadIdx.x & 63;
    if (wave_id >= N_E) return;
    const float* row = W + (size_t)wave_id * E_DIM;
    float4 v0 = *(const float4*)(row + lane * 4);
    float4 v1 = *(const float4*)(row + 256 + lane * 4);
    float s = v0.x*v0.x + v0.y*v0.y + v0.z*v0.z + v0.w*v0.w
            + v1.x*v1.x + v1.y*v1.y + v1.z*v1.z + v1.w*v1.w;
    #pragma unroll
    for (int off = 32; off; off >>= 1) s += __shfl_down(s, off);
    if (lane == 0) wnorm[wave_id] = s;
}

struct Top2 { float v0, v1; int i0, i1; };

__device__ inline Top2 merge2(Top2 A, Top2 B) {
    bool af = (A.v0 < B.v0) || (A.v0 == B.v0 && A.i0 < B.i0);
    float Wv1 = af ? A.v1 : B.v1; int Wi1 = af ? A.i1 : B.i1;
    float Lv0 = af ? B.v0 : A.v0; int Li0 = af ? B.i0 : A.i0;
    bool s2 = (Wv1 < Lv0) || (Wv1 == Lv0 && Wi1 < Li0);
    Top2 R;
    R.v0 = af ? A.v0 : B.v0; R.i0 = af ? A.i0 : B.i0;
    R.v1 = s2 ? Wv1 : Lv0;   R.i1 = s2 ? Wi1 : Li0;
    return R;
}

// ---------------- fp16 MFMA screen (K=512) + per-row top-2 per QUARTER ----------------
// Screen semantics identical to the PASSING R4..R10 configs. Structural change:
// A (the block's 32 z-rows, full K) is LDS-RESIDENT -- staged ONCE in the
// prologue (32 KB, ks-major [16][32 rows][64 B] so reads keep the proven 64B-row
// -stride + XOR-involution bank-clean layout). Steady state streams ONLY B
// through a 4-slot counted-vmcnt pipeline (2 gl_lds/thread/step, vmcnt(4)).
// Kills the A-restage L2-thrash -> HBM-latency stalls diagnosed in R10
// (FETCH 667 MB vs 145 MB compulsory). LDS 64 KB/block -> 2 blocks/CU.
__global__ __launch_bounds__(256, 2) void argmin_mfma(
        const ushort* __restrict__ Zh, const ushort* __restrict__ Wh,
        const float* __restrict__ wnorm, int* __restrict__ cand) {
    __shared__ __align__(16) char Lds[65536];   // [0,32K) A resident; [32K,64K) 4 B slots

    const int t = threadIdx.x;
    const int lane = t & 63;
    const int wid = t >> 6;            // 0..3 = wave_n (32-col chunk)
    const int l15 = lane & 15, l4 = lane >> 4;

    // chunked XCD remap (4096 blocks, 8 XCDs, 512-block chunks; bijective).
    const int id = blockIdx.x;
    const int orig = (id & 7) * 512 + (id >> 3);
    const int quarter = orig >> 10;    // 2 XCDs per quarter
    const int rowblk = orig & 1023;
    const int row0 = rowblk * BM;
    const int ebase = quarter * EQ;

    // ---- A prologue staging: 32 rows x 512 k, ks-major [ks][row][chunk] ----
    // LDS chunk c = j*256+t -> ks = j*2+(t>>7), row = (t>>2)&31, jj = t&3.
    // Swizzle on the GLOBAL side (LDS dest linear, rule #21): chunk ^= (row>>1)&3.
    const int arow = (t >> 2) & 31;
    const int aswz = (t & 3) ^ ((arow >> 1) & 3);
    const ushort* Ag = Zh + (size_t)(row0 + arow) * E_DIM + (t >> 7) * 32 + aswz * 8;
    #pragma unroll
    for (int j = 0; j < 8; j++)
        gl_lds16(Ag + j * 64, Lds + j * 4096 + t * 16);

    // ---- B staging bases (layout/swizzle identical to R10) ----
    const int bcol = t >> 2;
    const int bswz = (t & 3) ^ ((bcol >> 1) & 3);
    const ushort* Bc0 = Wh + (size_t)(ebase + bcol) * E_DIM + bswz * 8;   // cols 0-63
    const ushort* Bc1 = Bc0 + (size_t)64 * E_DIM;                        // cols 64-127

    // prologue B: slots 0,1,2 = ks 0,1,2 of e0-tile 0
    #pragma unroll
    for (int s = 0; s < 3; s++) {
        gl_lds16(Bc0 + s * 32, Lds + 32768 + s * 8192 + t * 16);
        gl_lds16(Bc1 + s * 32, Lds + 32768 + s * 8192 + 4096 + t * 16);
    }

    // fragment read bases (same involution), static offsets from here
    const int kchunk_b = (l4 ^ ((l15 >> 1) & 3)) * 16;
    const char* const ldsA = Lds + l15 * 64 + kchunk_b;            // + p*2048 + mi*1024
    const char* const ldsB = Lds + 32768 + wid * 2048 + l15 * 64 + kchunk_b; // + slot*8192 + ni*1024

    // wnorm prefetch base (2 per-lane values per e0-tile)
    const float* wn_ptr = wnorm + ebase + wid * 32 + l15;

    // per-thread top2 over 8 row-slots q=mi*4+r; row = mi*16 + l4*4 + r
    float v0[8], v1[8];
    int i0[8], i1[8];
    #pragma unroll
    for (int q = 0; q < 8; q++) { v0[q] = FLT_MAX; v1[q] = FLT_MAX; i0[q] = 0; i1[q] = 0; }

    f32x4 acc[2][2];
    #pragma unroll
    for (int mi = 0; mi < 2; mi++)
        #pragma unroll
        for (int ni = 0; ni < 2; ni++)
            acc[mi][ni] = (f32x4){0.f, 0.f, 0.f, 0.f};

    // step s = e0*16+p reads slot p&3 (ks=p); stages step s+3 into slot (p+3)&3.
    // At wait of step s: outstanding = B-stages of slots s+1,s+2 (4 loads) -> vmcnt(4).
    // Prologue A(8)+B(6): step-0 vmcnt(4) completes all A + slot0. Tail 4/2/0.
    #define BODY(P_, VMSTR, DOSTG, NEXTT) do {                                   \
        asm volatile("s_waitcnt " VMSTR ::: "memory");                           \
        __builtin_amdgcn_s_barrier();                                            \
        __builtin_amdgcn_sched_barrier(0);                                       \
        if (DOSTG) {                                                             \
            constexpr int _ss = 32768 + (((P_) + 3) & 3) * 8192;                 \
            constexpr int _ke = (((P_) + 3) & 15) * 32 + ((NEXTT) ? 65536 : 0);  \
            gl_lds16(Bc0 + _ke, Lds + _ss + t * 16);                             \
            gl_lds16(Bc1 + _ke, Lds + _ss + 4096 + t * 16);                      \
        }                                                                        \
        {                                                                        \
            const char* _sa = ldsA + (P_) * 2048;                                \
            const char* _sb = ldsB + ((P_) & 3) * 8192;                          \
            half8 a0_ = *(const half8*)(_sa);                                    \
            half8 a1_ = *(const half8*)(_sa + 1024);                             \
            half8 b0_ = *(const half8*)(_sb);                                    \
            half8 b1_ = *(const half8*)(_sb + 1024);                             \
            __builtin_amdgcn_s_setprio(1);                                       \
            acc[0][0] = __builtin_amdgcn_mfma_f32_16x16x32_f16(a0_, b0_, acc[0][0], 0, 0, 0); \
            acc[0][1] = __builtin_amdgcn_mfma_f32_16x16x32_f16(a0_, b1_, acc[0][1], 0, 0, 0); \
            acc[1][0] = __builtin_amdgcn_mfma_f32_16x16x32_f16(a1_, b0_, acc[1][0], 0, 0, 0); \
            acc[1][1] = __builtin_amdgcn_mfma_f32_16x16x32_f16(a1_, b1_, acc[1][1], 0, 0, 0); \
            __builtin_amdgcn_s_setprio(0);                                       \
        }                                                                        \
    } while (0)

    for (int e0 = 0; e0 < 16; ++e0) {
        float wn0 = wn_ptr[0];
        float wn1 = wn_ptr[16];

        BODY(0,  "vmcnt(4)", 1, 0);
        BODY(1,  "vmcnt(4)", 1, 0);
        BODY(2,  "vmcnt(4)", 1, 0);
        BODY(3,  "vmcnt(4)", 1, 0);
        BODY(4,  "vmcnt(4)", 1, 0);
        BODY(5,  "vmcnt(4)", 1, 0);
        BODY(6,  "vmcnt(4)", 1, 0);
        BODY(7,  "vmcnt(4)", 1, 0);
        BODY(8,  "vmcnt(4)", 1, 0);
        BODY(9,  "vmcnt(4)", 1, 0);
        BODY(10, "vmcnt(4)", 1, 0);
        BODY(11, "vmcnt(4)", 1, 0);
        BODY(12, "vmcnt(4)", 1, 0);
        if (e0 < 15) {
            BODY(13, "vmcnt(4)", 1, 1);   // stage ks 0..2 of NEXT tile
            BODY(14, "vmcnt(4)", 1, 1);
            BODY(15, "vmcnt(4)", 1, 1);
        } else {
            BODY(13, "vmcnt(4)", 0, 0);
            BODY(14, "vmcnt(2)", 0, 0);
            BODY(15, "vmcnt(0)", 0, 0);
        }

        // fold: score = wnorm[e] - 2*dot; D: col=lane&15, row=(lane>>4)*4+reg
        {
            int colb = ebase + e0 * BN + wid * 32 + l15;
            #pragma unroll
            for (int ni = 0; ni < 2; ni++) {
                int col = colb + ni * 16;
                float wn = (ni == 0) ? wn0 : wn1;
                #pragma unroll
                for (int mi = 0; mi < 2; mi++)
                    #pragma unroll
                    for (int r = 0; r < 4; r++) {
                        float sc = fmaf(-2.0f, acc[mi][ni][r], wn);
                        int q = mi * 4 + r;
                        if (sc < v0[q])      { v1[q] = v0[q]; i1[q] = i0[q]; v0[q] = sc; i0[q] = col; }
                        else if (sc < v1[q]) { v1[q] = sc; i1[q] = col; }
                    }
            }
            #pragma unroll
            for (int mi = 0; mi < 2; mi++)
                #pragma unroll
                for (int ni = 0; ni < 2; ni++)
                    acc[mi][ni] = (f32x4){0.f, 0.f, 0.f, 0.f};
        }

        wn_ptr += BN;
        Bc0 += (size_t)BN * E_DIM;
        Bc1 += (size_t)BN * E_DIM;
    }
    #undef BODY

    // merge buffer aliased into the B-slot region (B dead after main loop)
    __syncthreads();
    float4* SmTop = (float4*)(Lds + 32768);   // [32 rows][4 waves]

    #pragma unroll
    for (int mi = 0; mi < 2; mi++)
        #pragma unroll
        for (int r = 0; r < 4; r++) {
            int q = mi * 4 + r;
            Top2 T = {v0[q], v1[q], i0[q], i1[q]};
            #pragma unroll
            for (int mk = 1; mk <= 8; mk <<= 1) {
                Top2 O;
                O.v0 = __shfl_xor(T.v0, mk); O.v1 = __shfl_xor(T.v1, mk);
                O.i0 = __shfl_xor(T.i0, mk); O.i1 = __shfl_xor(T.i1, mk);
                T = merge2(T, O);
            }
            if (l15 == 0) {
                int rl = mi * 16 + l4 * 4 + r;
                SmTop[rl * 4 + wid] = make_float4(T.v0, __int_as_float(T.i0), T.v1, __int_as_float(T.i1));
            }
        }
    __syncthreads();
    if (t < BM) {
        Top2 q[4];
        #pragma unroll
        for (int j = 0; j < 4; j++) {
            float4 F = SmTop[t * 4 + j];
            q[j].v0 = F.x; q[j].i0 = __float_as_int(F.y);
            q[j].v1 = F.z; q[j].i1 = __float_as_int(F.w);
        }
        Top2 T = merge2(merge2(q[0], q[1]), merge2(q[2], q[3]));
        cand[(size_t)(row0 + t) * (2 * NQ) + quarter * 2 + 0] = T.i0;
        cand[(size_t)(row0 + t) * (2 * NQ) + quarter * 2 + 1] = T.i1;
    }
}

// ---------------- fp32 rescore of 8 candidates + gather z_q + loss partial ----------------
__global__ __launch_bounds__(256) void rescore_gather_loss(
        const float* __restrict__ Z, const float* __restrict__ W,
        const float* __restrict__ wnorm, const int* __restrict__ cand,
        float* __restrict__ out, float* __restrict__ partials) {
    const int n = blockIdx.x;
    const int t = threadIdx.x;
    const int lane = t & 63, wv = t >> 6;
    int c[8];
    #pragma unroll
    for (int j = 0; j < 8; j++) c[j] = cand[(size_t)n * 8 + j];
    float2 zv = ((const float2*)(Z + (size_t)n * E_DIM))[t];
    float2 wvv[8];
    #pragma unroll
    for (int j = 0; j < 8; j++)
        wvv[j] = ((const float2*)(W + (size_t)c[j] * E_DIM))[t];
    __shared__ float red[4][8];
    #pragma unroll
    for (int j = 0; j < 8; j++) {
        float s = zv.x * wvv[j].x + zv.y * wvv[j].y;
        #pragma unroll
        for (int off = 32; off; off >>= 1) s += __shfl_down(s, off);
        if (lane == 0) red[wv][j] = s;
    }
    __syncthreads();
    float best = FLT_MAX; int bj = 0, bc = 0x7fffffff;
    #pragma unroll
    for (int j = 0; j < 8; j++) {
        float d = red[0][j] + red[1][j] + red[2][j] + red[3][j];
        float s = wnorm[c[j]] - 2.0f * d;
        if (s < best || (s == best && c[j] < bc)) { best = s; bj = j; bc = c[j]; }
    }
    float2 wq = wvv[0];                 // static-index select (rule #20)
    #pragma unroll
    for (int j = 1; j < 8; j++) if (bj == j) wq = wvv[j];
    ((float2*)(out + 1 + (size_t)n * E_DIM))[t] = wq;   // z_q_st == z_q numerically
    float d0 = wq.x - zv.x, d1 = wq.y - zv.y;
    float sl = d0 * d0 + d1 * d1;
    #pragma unroll
    for (int off = 32; off; off >>= 1) sl += __shfl_down(sl, off);
    __shared__ float red2[4];
    if (lane == 0) red2[wv] = sl;
    __syncthreads();
    if (t == 0) {
        partials[n] = red2[0] + red2[1] + red2[2] + red2[3];
        out[1 + (size_t)M_ROWS * E_DIM + n] = (float)bc;
    }
}

// ---------------- deterministic final loss reduction ----------------
__global__ __launch_bounds__(256) void loss_reduce_kernel(const float* __restrict__ partials,
                                                          float* __restrict__ out) {
    const int t = threadIdx.x;
    float s = 0.0f;
    for (int i = t; i < M_ROWS; i += 256) s += partials[i];
    #pragma unroll
    for (int off = 32; off; off >>= 1) s += __shfl_down(s, off);
    __shared__ float red[4];
    if ((t & 63) == 0) red[t >> 6] = s;
    __syncthreads();
    if (t == 0) {
        float total = red[0] + red[1] + red[2] + red[3];
        out[0] = 2.0f * total / ((float)M_ROWS * (float)E_DIM);  // beta=1 collapses
    }
}

extern "C" void kernel_launch(void* const* d_in, const int* in_sizes, int n_in,
                              void* d_out, int out_size, void* d_ws, size_t ws_size,
                              hipStream_t stream) {
    const float* Z = (const float*)d_in[0];
    const float* W = (const float*)d_in[1];
    float* out = (float*)d_out;

    char* p = (char*)d_ws;
    ushort* Zh = (ushort*)p;      p += (size_t)M_ROWS * E_DIM * 2;
    ushort* Wh = (ushort*)p;      p += (size_t)N_E * E_DIM * 2;
    float* wnorm = (float*)p;     p += (size_t)N_E * 4;
    int* cand = (int*)p;          p += (size_t)M_ROWS * 8 * 4;
    float* partials = (float*)p;  p += (size_t)M_ROWS * 4;

    f16_cast_kernel<<<(M_ROWS * E_DIM / 4 + 255) / 256, 256, 0, stream>>>(Z, Zh, M_ROWS * E_DIM / 4);
    f16_cast_kernel<<<(N_E * E_DIM / 4 + 255) / 256, 256, 0, stream>>>(W, Wh, N_E * E_DIM / 4);
    wnorm_kernel<<<N_E / 4, 256, 0, stream>>>(W, wnorm);
    argmin_mfma<<<NQ * (M_ROWS / BM), 256, 0, stream>>>(Zh, Wh, wnorm, cand);
    rescore_gather_loss<<<M_ROWS, 256, 0, stream>>>(Z, W, wnorm, cand, out, partials);
    loss_reduce_kernel<<<1, 256, 0, stream>>>(partials, out);
}

// Round 12
// 690.293 us; speedup vs baseline: 1.4293x; 1.0637x over previous
//
#include <hip/hip_runtime.h>
#include <hip/hip_fp16.h>
#include <float.h>

#define M_ROWS 32768
#define E_DIM  512
#define N_E    8192

#define BM 32
#define BN 128
#define BK 32
#define NQ 4                    // quarters of the e-range
#define EQ (N_E / NQ)           // 2048 codes per quarter

typedef __attribute__((ext_vector_type(8))) _Float16 half8;
typedef __attribute__((ext_vector_type(4))) float f32x4;

// offset arg ALWAYS 0 (m97-proven semantics; R9: imm-offset arg is NOT a plain
// global add on gfx950). Constant offsets folded into the pointer.
__device__ __forceinline__ void gl_lds16(const void* g, void* l) {
    __builtin_amdgcn_global_load_lds(
        (const __attribute__((address_space(1))) unsigned int*)g,
        (__attribute__((address_space(3))) unsigned int*)l, 16, 0, 0);
}

// ---------------- fp32 -> fp16 (RTNE) ----------------
__global__ __launch_bounds__(256) void f16_cast_kernel(const float* __restrict__ X,
                                                       ushort* __restrict__ H,
                                                       int n4) {
    int i = blockIdx.x * 256 + threadIdx.x;
    if (i >= n4) return;
    float4 v = ((const float4*)X)[i];
    float c[4] = {v.x, v.y, v.z, v.w};
    ushort hh[4];
    #pragma unroll
    for (int j = 0; j < 4; j++) {
        __half hb = __float2half(c[j]);
        hh[j] = *(ushort*)&hb;
    }
    ushort4 h = {hh[0], hh[1], hh[2], hh[3]};
    ((ushort4*)H)[i] = h;
}

// ---------------- wnorm[e] = sum_k W[e][k]^2 (fp32, exact) ----------------
__global__ __launch_bounds__(256) void wnorm_kernel(const float* __restrict__ W,
                                                    float* __restrict__ wnorm) {
    int wave_id = (int)((blockIdx.x * blockDim.x + threadIdx.x) >> 6);
    int lane = threadIdx.x & 63;
    if (wave_id >= N_E) return;
    const float* row = W + (size_t)wave_id * E_DIM;
    float4 v0 = *(const float4*)(row + lane * 4);
    float4 v1 = *(const float4*)(row + 256 + lane * 4);
    float s = v0.x*v0.x + v0.y*v0.y + v0.z*v0.z + v0.w*v0.w
            + v1.x*v1.x + v1.y*v1.y + v1.z*v1.z + v1.w*v1.w;
    #pragma unroll
    for (int off = 32; off; off >>= 1) s += __shfl_down(s, off);
    if (lane == 0) wnorm[wave_id] = s;
}

struct Top2 { float v0, v1; int i0, i1; };

__device__ inline Top2 merge2(Top2 A, Top2 B) {
    bool af = (A.v0 < B.v0) || (A.v0 == B.v0 && A.i0 < B.i0);
    float Wv1 = af ? A.v1 : B.v1; int Wi1 = af ? A.i1 : B.i1;
    float Lv0 = af ? B.v0 : A.v0; int Li0 = af ? B.i0 : A.i0;
    bool s2 = (Wv1 < Lv0) || (Wv1 == Lv0 && Wi1 < Li0);
    Top2 R;
    R.v0 = af ? A.v0 : B.v0; R.i0 = af ? A.i0 : B.i0;
    R.v1 = s2 ? Wv1 : Lv0;   R.i1 = s2 ? Wi1 : Li0;
    return R;
}

// ---------------- fp16 MFMA screen (K=512) + per-row top-2 per QUARTER ----------------
// Screen semantics identical to the PASSING R4..R11 configs. Execution changes:
//  * A FRAGMENTS IN REGISTERS: A staged to LDS once (R11 path), read once into
//    Areg[32] (128 VGPR), then the same 32 KB LDS is recycled as the 4 B slots.
//    Removes A ds_reads from every step (LDS traffic 24->16 KB/block-step) and
//    A never touches the per-step latency chain.
//  * B REGISTER PREFETCH: vmcnt(2) at each barrier (stricter than R11's 4) makes
//    slot s+1 globally valid at barrier s -> ds_read next step's B during this
//    step's MFMA (Bf[2][2] parity regs, static indices). ds latency off the
//    critical path.
//  * 4-slot counted-vmcnt pipeline otherwise frozen (stage 3 ahead, tail peel).
__global__ __launch_bounds__(256, 2) void argmin_mfma(
        const ushort* __restrict__ Zh, const ushort* __restrict__ Wh,
        const float* __restrict__ wnorm, int* __restrict__ cand) {
    __shared__ __align__(16) char Lds[32768];   // A prologue, then 4 B slots of 8 KB

    const int t = threadIdx.x;
    const int lane = t & 63;
    const int wid = t >> 6;            // 0..3 = wave_n (32-col chunk)
    const int l15 = lane & 15, l4 = lane >> 4;

    // chunked XCD remap (4096 blocks, 8 XCDs, 512-block chunks; bijective).
    const int id = blockIdx.x;
    const int orig = (id & 7) * 512 + (id >> 3);
    const int quarter = orig >> 10;    // 2 XCDs per quarter
    const int rowblk = orig & 1023;
    const int row0 = rowblk * BM;
    const int ebase = quarter * EQ;

    // ---- A prologue staging: 32 rows x 512 k, ks-major [ks][row][chunk] ----
    // Swizzle on the GLOBAL side (LDS dest linear, rule #21): chunk ^= (row>>1)&3.
    const int arow = (t >> 2) & 31;
    const int aswz = (t & 3) ^ ((arow >> 1) & 3);
    const ushort* Ag = Zh + (size_t)(row0 + arow) * E_DIM + (t >> 7) * 32 + aswz * 8;
    #pragma unroll
    for (int j = 0; j < 8; j++)
        gl_lds16(Ag + j * 64, Lds + j * 4096 + t * 16);

    asm volatile("s_waitcnt vmcnt(0)" ::: "memory");
    __builtin_amdgcn_s_barrier();
    __builtin_amdgcn_sched_barrier(0);

    // ---- A fragments -> registers (same involution as staging) ----
    const int kchunk_b = (l4 ^ ((l15 >> 1) & 3)) * 16;
    half8 Areg[32];
    #pragma unroll
    for (int ks = 0; ks < 16; ks++)
        #pragma unroll
        for (int mi = 0; mi < 2; mi++)
            Areg[ks * 2 + mi] = *(const half8*)(Lds + ks * 2048 + (mi * 16 + l15) * 64 + kchunk_b);

    asm volatile("s_waitcnt lgkmcnt(0)" ::: "memory");
    __builtin_amdgcn_sched_barrier(0);
    __builtin_amdgcn_s_barrier();      // all waves done reading A before B overwrites
    __builtin_amdgcn_sched_barrier(0);

    // ---- B staging bases (layout/swizzle identical to R11) ----
    const int bcol = t >> 2;
    const int bswz = (t & 3) ^ ((bcol >> 1) & 3);
    const ushort* Bc0 = Wh + (size_t)(ebase + bcol) * E_DIM + bswz * 8;   // cols 0-63
    const ushort* Bc1 = Bc0 + (size_t)64 * E_DIM;                        // cols 64-127

    // prologue B: slots 0,1,2 = ks 0,1,2 of e0-tile 0
    #pragma unroll
    for (int s = 0; s < 3; s++) {
        gl_lds16(Bc0 + s * 32, Lds + s * 8192 + t * 16);
        gl_lds16(Bc1 + s * 32, Lds + s * 8192 + 4096 + t * 16);
    }

    const char* const ldsB = Lds + wid * 2048 + l15 * 64 + kchunk_b;  // + slot*8192 + ni*1024
    const float* wn_ptr = wnorm + ebase + wid * 32 + l15;

    // per-thread top2 over 8 row-slots q=mi*4+r; row = mi*16 + l4*4 + r
    float v0[8], v1[8];
    int i0[8], i1[8];
    #pragma unroll
    for (int q = 0; q < 8; q++) { v0[q] = FLT_MAX; v1[q] = FLT_MAX; i0[q] = 0; i1[q] = 0; }

    f32x4 acc[2][2];
    #pragma unroll
    for (int mi = 0; mi < 2; mi++)
        #pragma unroll
        for (int ni = 0; ni < 2; ni++)
            acc[mi][ni] = (f32x4){0.f, 0.f, 0.f, 0.f};

    half8 Bf[2][2];   // parity-indexed (all indices compile-time)

    // pre-loop: slot 0 -> Bf[0]
    asm volatile("s_waitcnt vmcnt(4)" ::: "memory");   // force stage(0); allow 1,2
    __builtin_amdgcn_s_barrier();
    __builtin_amdgcn_sched_barrier(0);
    Bf[0][0] = *(const half8*)(ldsB);
    Bf[0][1] = *(const half8*)(ldsB + 1024);

    // step P_ in [0,16) per tile. At wait of P_: forces stage(P_+1) complete
    // (needed: RDNXT reads slot P_+1), allows stage(P_+2) outstanding -> vmcnt(2).
    #define BODY(P_, VMSTR, DOSTG, NEXTT, RDNXT) do {                            \
        asm volatile("s_waitcnt " VMSTR ::: "memory");                           \
        __builtin_amdgcn_s_barrier();                                            \
        __builtin_amdgcn_sched_barrier(0);                                       \
        if (DOSTG) {                                                             \
            constexpr int _ss = (((P_) + 3) & 3) * 8192;                         \
            constexpr int _ke = (((P_) + 3) & 15) * 32 + ((NEXTT) ? 65536 : 0);  \
            gl_lds16(Bc0 + _ke, Lds + _ss + t * 16);                             \
            gl_lds16(Bc1 + _ke, Lds + _ss + 4096 + t * 16);                      \
        }                                                                        \
        if (RDNXT) {                                                             \
            const char* _sb = ldsB + (((P_) + 1) & 3) * 8192;                    \
            Bf[((P_) + 1) & 1][0] = *(const half8*)(_sb);                        \
            Bf[((P_) + 1) & 1][1] = *(const half8*)(_sb + 1024);                 \
        }                                                                        \
        __builtin_amdgcn_s_setprio(1);                                           \
        acc[0][0] = __builtin_amdgcn_mfma_f32_16x16x32_f16(Areg[(P_)*2+0], Bf[(P_)&1][0], acc[0][0], 0, 0, 0); \
        acc[0][1] = __builtin_amdgcn_mfma_f32_16x16x32_f16(Areg[(P_)*2+0], Bf[(P_)&1][1], acc[0][1], 0, 0, 0); \
        acc[1][0] = __builtin_amdgcn_mfma_f32_16x16x32_f16(Areg[(P_)*2+1], Bf[(P_)&1][0], acc[1][0], 0, 0, 0); \
        acc[1][1] = __builtin_amdgcn_mfma_f32_16x16x32_f16(Areg[(P_)*2+1], Bf[(P_)&1][1], acc[1][1], 0, 0, 0); \
        __builtin_amdgcn_s_setprio(0);                                           \
    } while (0)

    for (int e0 = 0; e0 < 16; ++e0) {
        float wn0 = wn_ptr[0];
        float wn1 = wn_ptr[16];

        BODY(0,  "vmcnt(2)", 1, 0, 1);
        BODY(1,  "vmcnt(2)", 1, 0, 1);
        BODY(2,  "vmcnt(2)", 1, 0, 1);
        BODY(3,  "vmcnt(2)", 1, 0, 1);
        BODY(4,  "vmcnt(2)", 1, 0, 1);
        BODY(5,  "vmcnt(2)", 1, 0, 1);
        BODY(6,  "vmcnt(2)", 1, 0, 1);
        BODY(7,  "vmcnt(2)", 1, 0, 1);
        BODY(8,  "vmcnt(2)", 1, 0, 1);
        BODY(9,  "vmcnt(2)", 1, 0, 1);
        BODY(10, "vmcnt(2)", 1, 0, 1);
        BODY(11, "vmcnt(2)", 1, 0, 1);
        BODY(12, "vmcnt(2)", 1, 0, 1);
        if (e0 < 15) {
            BODY(13, "vmcnt(2)", 1, 1, 1);   // stage ks 0..2 of NEXT tile
            BODY(14, "vmcnt(2)", 1, 1, 1);
            BODY(15, "vmcnt(2)", 1, 1, 1);   // RDNXT = next tile ks0 (slot 0)
        } else {
            BODY(13, "vmcnt(2)", 0, 0, 1);
            BODY(14, "vmcnt(0)", 0, 0, 1);
            BODY(15, "vmcnt(0)", 0, 0, 0);
        }

        // fold: score = wnorm[e] - 2*dot; D: col=lane&15, row=(lane>>4)*4+reg
        {
            int colb = ebase + e0 * BN + wid * 32 + l15;
            #pragma unroll
            for (int ni = 0; ni < 2; ni++) {
                int col = colb + ni * 16;
                float wn = (ni == 0) ? wn0 : wn1;
                #pragma unroll
                for (int mi = 0; mi < 2; mi++)
                    #pragma unroll
                    for (int r = 0; r < 4; r++) {
                        float sc = fmaf(-2.0f, acc[mi][ni][r], wn);
                        int q = mi * 4 + r;
                        if (sc < v0[q])      { v1[q] = v0[q]; i1[q] = i0[q]; v0[q] = sc; i0[q] = col; }
                        else if (sc < v1[q]) { v1[q] = sc; i1[q] = col; }
                    }
            }
            #pragma unroll
            for (int mi = 0; mi < 2; mi++)
                #pragma unroll
                for (int ni = 0; ni < 2; ni++)
                    acc[mi][ni] = (f32x4){0.f, 0.f, 0.f, 0.f};
        }

        wn_ptr += BN;
        Bc0 += (size_t)BN * E_DIM;
        Bc1 += (size_t)BN * E_DIM;
    }
    #undef BODY

    // merge buffer aliased into the slot region (B dead after main loop)
    __syncthreads();
    float4* SmTop = (float4*)Lds;   // [32 rows][4 waves]

    #pragma unroll
    for (int mi = 0; mi < 2; mi++)
        #pragma unroll
        for (int r = 0; r < 4; r++) {
            int q = mi * 4 + r;
            Top2 T = {v0[q], v1[q], i0[q], i1[q]};
            #pragma unroll
            for (int mk = 1; mk <= 8; mk <<= 1) {
                Top2 O;
                O.v0 = __shfl_xor(T.v0, mk); O.v1 = __shfl_xor(T.v1, mk);
                O.i0 = __shfl_xor(T.i0, mk); O.i1 = __shfl_xor(T.i1, mk);
                T = merge2(T, O);
            }
            if (l15 == 0) {
                int rl = mi * 16 + l4 * 4 + r;
                SmTop[rl * 4 + wid] = make_float4(T.v0, __int_as_float(T.i0), T.v1, __int_as_float(T.i1));
            }
        }
    __syncthreads();
    if (t < BM) {
        Top2 q[4];
        #pragma unroll
        for (int j = 0; j < 4; j++) {
            float4 F = SmTop[t * 4 + j];
            q[j].v0 = F.x; q[j].i0 = __float_as_int(F.y);
            q[j].v1 = F.z; q[j].i1 = __float_as_int(F.w);
        }
        Top2 T = merge2(merge2(q[0], q[1]), merge2(q[2], q[3]));
        cand[(size_t)(row0 + t) * (2 * NQ) + quarter * 2 + 0] = T.i0;
        cand[(size_t)(row0 + t) * (2 * NQ) + quarter * 2 + 1] = T.i1;
    }
}

// ---------------- fp32 rescore of 8 candidates + gather z_q + loss partial ----------------
__global__ __launch_bounds__(256) void rescore_gather_loss(
        const float* __restrict__ Z, const float* __restrict__ W,
        const float* __restrict__ wnorm, const int* __restrict__ cand,
        float* __restrict__ out, float* __restrict__ partials) {
    const int n = blockIdx.x;
    const int t = threadIdx.x;
    const int lane = t & 63, wv = t >> 6;
    int c[8];
    #pragma unroll
    for (int j = 0; j < 8; j++) c[j] = cand[(size_t)n * 8 + j];
    float2 zv = ((const float2*)(Z + (size_t)n * E_DIM))[t];
    float2 wvv[8];
    #pragma unroll
    for (int j = 0; j < 8; j++)
        wvv[j] = ((const float2*)(W + (size_t)c[j] * E_DIM))[t];
    __shared__ float red[4][8];
    #pragma unroll
    for (int j = 0; j < 8; j++) {
        float s = zv.x * wvv[j].x + zv.y * wvv[j].y;
        #pragma unroll
        for (int off = 32; off; off >>= 1) s += __shfl_down(s, off);
        if (lane == 0) red[wv][j] = s;
    }
    __syncthreads();
    float best = FLT_MAX; int bj = 0, bc = 0x7fffffff;
    #pragma unroll
    for (int j = 0; j < 8; j++) {
        float d = red[0][j] + red[1][j] + red[2][j] + red[3][j];
        float s = wnorm[c[j]] - 2.0f * d;
        if (s < best || (s == best && c[j] < bc)) { best = s; bj = j; bc = c[j]; }
    }
    float2 wq = wvv[0];                 // static-index select (rule #20)
    #pragma unroll
    for (int j = 1; j < 8; j++) if (bj == j) wq = wvv[j];
    ((float2*)(out + 1 + (size_t)n * E_DIM))[t] = wq;   // z_q_st == z_q numerically
    float d0 = wq.x - zv.x, d1 = wq.y - zv.y;
    float sl = d0 * d0 + d1 * d1;
    #pragma unroll
    for (int off = 32; off; off >>= 1) sl += __shfl_down(sl, off);
    __shared__ float red2[4];
    if (lane == 0) red2[wv] = sl;
    __syncthreads();
    if (t == 0) {
        partials[n] = red2[0] + red2[1] + red2[2] + red2[3];
        out[1 + (size_t)M_ROWS * E_DIM + n] = (float)bc;
    }
}

// ---------------- deterministic final loss reduction ----------------
__global__ __launch_bounds__(256) void loss_reduce_kernel(const float* __restrict__ partials,
                                                          float* __restrict__ out) {
    const int t = threadIdx.x;
    float s = 0.0f;
    for (int i = t; i < M_ROWS; i += 256) s += partials[i];
    #pragma unroll
    for (int off = 32; off; off >>= 1) s += __shfl_down(s, off);
    __shared__ float red[4];
    if ((t & 63) == 0) red[t >> 6] = s;
    __syncthreads();
    if (t == 0) {
        float total = red[0] + red[1] + red[2] + red[3];
        out[0] = 2.0f * total / ((float)M_ROWS * (float)E_DIM);  // beta=1 collapses
    }
}

extern "C" void kernel_launch(void* const* d_in, const int* in_sizes, int n_in,
                              void* d_out, int out_size, void* d_ws, size_t ws_size,
                              hipStream_t stream) {
    const float* Z = (const float*)d_in[0];
    const float* W = (const float*)d_in[1];
    float* out = (float*)d_out;

    char* p = (char*)d_ws;
    ushort* Zh = (ushort*)p;      p += (size_t)M_ROWS * E_DIM * 2;
    ushort* Wh = (ushort*)p;      p += (size_t)N_E * E_DIM * 2;
    float* wnorm = (float*)p;     p += (size_t)N_E * 4;
    int* cand = (int*)p;          p += (size_t)M_ROWS * 8 * 4;
    float* partials = (float*)p;  p += (size_t)M_ROWS * 4;

    f16_cast_kernel<<<(M_ROWS * E_DIM / 4 + 255) / 256, 256, 0, stream>>>(Z, Zh, M_ROWS * E_DIM / 4);
    f16_cast_kernel<<<(N_E * E_DIM / 4 + 255) / 256, 256, 0, stream>>>(W, Wh, N_E * E_DIM / 4);
    wnorm_kernel<<<N_E / 4, 256, 0, stream>>>(W, wnorm);
    argmin_mfma<<<NQ * (M_ROWS / BM), 256, 0, stream>>>(Zh, Wh, wnorm, cand);
    rescore_gather_loss<<<M_ROWS, 256, 0, stream>>>(Z, W, wnorm, cand, out, partials);
    loss_reduce_kernel<<<1, 256, 0, stream>>>(partials, out);
}

// Round 13
// 662.888 us; speedup vs baseline: 1.4884x; 1.0413x over previous
//
#include <hip/hip_runtime.h>
#include <hip/hip_fp16.h>
#include <float.h>

#define M_ROWS 32768
#define E_DIM  512
#define N_E    8192

#define BM 32
#define BN 128
#define BK 32
#define NQ 4                    // quarters of the e-range
#define EQ (N_E / NQ)           // 2048 codes per quarter

typedef __attribute__((ext_vector_type(8))) _Float16 half8;
typedef __attribute__((ext_vector_type(4))) float f32x4;

// offset arg ALWAYS 0 (m97-proven semantics; R9: imm-offset arg is NOT a plain
// global add on gfx950). Constant offsets folded into the pointer.
__device__ __forceinline__ void gl_lds16(const void* g, void* l) {
    __builtin_amdgcn_global_load_lds(
        (const __attribute__((address_space(1))) unsigned int*)g,
        (__attribute__((address_space(3))) unsigned int*)l, 16, 0, 0);
}

#define MFMA16(A_, B_, C_) __builtin_amdgcn_mfma_f32_16x16x32_f16((A_), (B_), (C_), 0, 0, 0)

// ---------------- fp32 -> fp16 (RTNE) ----------------
__global__ __launch_bounds__(256) void f16_cast_kernel(const float* __restrict__ X,
                                                       ushort* __restrict__ H,
                                                       int n4) {
    int i = blockIdx.x * 256 + threadIdx.x;
    if (i >= n4) return;
    float4 v = ((const float4*)X)[i];
    float c[4] = {v.x, v.y, v.z, v.w};
    ushort hh[4];
    #pragma unroll
    for (int j = 0; j < 4; j++) {
        __half hb = __float2half(c[j]);
        hh[j] = *(ushort*)&hb;
    }
    ushort4 h = {hh[0], hh[1], hh[2], hh[3]};
    ((ushort4*)H)[i] = h;
}

// ---------------- wnorm[e] = sum_k W[e][k]^2 (fp32, exact) ----------------
__global__ __launch_bounds__(256) void wnorm_kernel(const float* __restrict__ W,
                                                    float* __restrict__ wnorm) {
    int wave_id = (int)((blockIdx.x * blockDim.x + threadIdx.x) >> 6);
    int lane = threadIdx.x & 63;
    if (wave_id >= N_E) return;
    const float* row = W + (size_t)wave_id * E_DIM;
    float4 v0 = *(const float4*)(row + lane * 4);
    float4 v1 = *(const float4*)(row + 256 + lane * 4);
    float s = v0.x*v0.x + v0.y*v0.y + v0.z*v0.z + v0.w*v0.w
            + v1.x*v1.x + v1.y*v1.y + v1.z*v1.z + v1.w*v1.w;
    #pragma unroll
    for (int off = 32; off; off >>= 1) s += __shfl_down(s, off);
    if (lane == 0) wnorm[wave_id] = s;
}

struct Top2 { float v0, v1; int i0, i1; };

__device__ inline Top2 merge2(Top2 A, Top2 B) {
    bool af = (A.v0 < B.v0) || (A.v0 == B.v0 && A.i0 < B.i0);
    float Wv1 = af ? A.v1 : B.v1; int Wi1 = af ? A.i1 : B.i1;
    float Lv0 = af ? B.v0 : A.v0; int Li0 = af ? B.i0 : A.i0;
    bool s2 = (Wv1 < Lv0) || (Wv1 == Lv0 && Wi1 < Li0);
    Top2 R;
    R.v0 = af ? A.v0 : B.v0; R.i0 = af ? A.i0 : B.i0;
    R.v1 = s2 ? Wv1 : Lv0;   R.i1 = s2 ? Wi1 : Li0;
    return R;
}

// ---------------- fp16 MFMA screen (K=512) + per-row top-2 per QUARTER ----------------
// Screen semantics identical to the PASSING R4..R12 configs. Execution change vs
// R12 (which measured as per-step-sync-bound: nothing saturated, 256 barriers/
// sweep with only 4 MFMA each): PAIR-STEPS -- one vmcnt+barrier per K=64 (8 MFMA,
// 4 B ds_reads, 4 stage loads), 128 steps. 8 LDS slots (64 KB). B regs are a
// fixed even/odd ping-pong: X=B(even ks), Y=B(odd ks); at step Q read Y(2Q+1)
// post-barrier, MFMA(2Q) on X, refill X<-B(2Q+2) (vmcnt(2)-forced), MFMA(2Q+1).
// A in registers (Areg[32]), XOR swizzle, fold/merge frozen from R12.
__global__ __launch_bounds__(256, 2) void argmin_mfma(
        const ushort* __restrict__ Zh, const ushort* __restrict__ Wh,
        const float* __restrict__ wnorm, int* __restrict__ cand) {
    __shared__ __align__(16) char Lds[65536];   // A prologue in [0,32K), then 8 B slots

    const int t = threadIdx.x;
    const int lane = t & 63;
    const int wid = t >> 6;            // 0..3 = wave_n (32-col chunk)
    const int l15 = lane & 15, l4 = lane >> 4;

    // chunked XCD remap (4096 blocks, 8 XCDs, 512-block chunks; bijective).
    const int id = blockIdx.x;
    const int orig = (id & 7) * 512 + (id >> 3);
    const int quarter = orig >> 10;    // 2 XCDs per quarter
    const int rowblk = orig & 1023;
    const int row0 = rowblk * BM;
    const int ebase = quarter * EQ;

    // ---- A prologue staging: 32 rows x 512 k, ks-major [ks][row][chunk] ----
    // Swizzle on the GLOBAL side (LDS dest linear, rule #21): chunk ^= (row>>1)&3.
    const int arow = (t >> 2) & 31;
    const int aswz = (t & 3) ^ ((arow >> 1) & 3);
    const ushort* Ag = Zh + (size_t)(row0 + arow) * E_DIM + (t >> 7) * 32 + aswz * 8;
    #pragma unroll
    for (int j = 0; j < 8; j++)
        gl_lds16(Ag + j * 64, Lds + j * 4096 + t * 16);

    asm volatile("s_waitcnt vmcnt(0)" ::: "memory");
    __builtin_amdgcn_s_barrier();
    __builtin_amdgcn_sched_barrier(0);

    // ---- A fragments -> registers (same involution as staging) ----
    const int kchunk_b = (l4 ^ ((l15 >> 1) & 3)) * 16;
    half8 Areg[32];
    #pragma unroll
    for (int ks = 0; ks < 16; ks++)
        #pragma unroll
        for (int mi = 0; mi < 2; mi++)
            Areg[ks * 2 + mi] = *(const half8*)(Lds + ks * 2048 + (mi * 16 + l15) * 64 + kchunk_b);

    asm volatile("s_waitcnt lgkmcnt(0)" ::: "memory");
    __builtin_amdgcn_sched_barrier(0);
    __builtin_amdgcn_s_barrier();      // all waves done reading A before B overwrites
    __builtin_amdgcn_sched_barrier(0);

    // ---- B staging bases (layout/swizzle identical to R12) ----
    const int bcol = t >> 2;
    const int bswz = (t & 3) ^ ((bcol >> 1) & 3);
    const ushort* Bc0 = Wh + (size_t)(ebase + bcol) * E_DIM + bswz * 8;   // cols 0-63
    const ushort* Bc1 = Bc0 + (size_t)64 * E_DIM;                        // cols 64-127

    // prologue B: slots 0..3 = ks 0..3 of e0-tile 0 (issue order = ks order)
    #pragma unroll
    for (int s = 0; s < 4; s++) {
        gl_lds16(Bc0 + s * 32, Lds + s * 8192 + t * 16);
        gl_lds16(Bc1 + s * 32, Lds + s * 8192 + 4096 + t * 16);
    }

    const char* const ldsB = Lds + wid * 2048 + l15 * 64 + kchunk_b;  // + slot*8192 + ni*1024
    const float* wn_ptr = wnorm + ebase + wid * 32 + l15;

    // per-thread top2 over 8 row-slots q=mi*4+r; row = mi*16 + l4*4 + r
    float v0[8], v1[8];
    int i0[8], i1[8];
    #pragma unroll
    for (int q = 0; q < 8; q++) { v0[q] = FLT_MAX; v1[q] = FLT_MAX; i0[q] = 0; i1[q] = 0; }

    f32x4 acc[2][2];
    #pragma unroll
    for (int mi = 0; mi < 2; mi++)
        #pragma unroll
        for (int ni = 0; ni < 2; ni++)
            acc[mi][ni] = (f32x4){0.f, 0.f, 0.f, 0.f};

    half8 Xf[2], Yf[2];   // X = even-ks B frags, Y = odd-ks

    // pre-loop: force ks0 (first 2 of the 8 prologue loads), read X<-B(0)
    asm volatile("s_waitcnt vmcnt(6)" ::: "memory");
    __builtin_amdgcn_s_barrier();
    __builtin_amdgcn_sched_barrier(0);
    Xf[0] = *(const half8*)(ldsB);
    Xf[1] = *(const half8*)(ldsB + 1024);

    // pair-step Q_ in [0,8) per tile (local ks 2Q,2Q+1). Stage ks 2Q+4,2Q+5 into
    // slots (2Q+4)&7,(2Q+5)&7. vmcnt(2): at wait, outstanding = stage(Q-1)'s 4
    // loads -> forces ks 2Q+2 (X refill), leaves ks 2Q+3 in flight.
    #define PBODY(Q_, VMSTR, DOSTG, NEXTT, RDX) do {                             \
        asm volatile("s_waitcnt " VMSTR ::: "memory");                           \
        __builtin_amdgcn_s_barrier();                                            \
        __builtin_amdgcn_sched_barrier(0);                                       \
        if (DOSTG) {                                                             \
            constexpr int _sa0 = ((2*(Q_)+4) & 7) * 8192;                        \
            constexpr int _sa1 = ((2*(Q_)+5) & 7) * 8192;                        \
            constexpr int _ke0 = ((2*(Q_)+4) & 15) * 32 + ((NEXTT) ? 65536 : 0); \
            constexpr int _ke1 = ((2*(Q_)+5) & 15) * 32 + ((NEXTT) ? 65536 : 0); \
            gl_lds16(Bc0 + _ke0, Lds + _sa0 + t * 16);                           \
            gl_lds16(Bc1 + _ke0, Lds + _sa0 + 4096 + t * 16);                    \
            gl_lds16(Bc0 + _ke1, Lds + _sa1 + t * 16);                           \
            gl_lds16(Bc1 + _ke1, Lds + _sa1 + 4096 + t * 16);                    \
        }                                                                        \
        {                                                                        \
            const char* _sy = ldsB + ((2*(Q_)+1) & 7) * 8192;                    \
            Yf[0] = *(const half8*)(_sy);                                        \
            Yf[1] = *(const half8*)(_sy + 1024);                                 \
        }                                                                        \
        __builtin_amdgcn_s_setprio(1);                                           \
        acc[0][0] = MFMA16(Areg[4*(Q_)+0], Xf[0], acc[0][0]);                    \
        acc[0][1] = MFMA16(Areg[4*(Q_)+0], Xf[1], acc[0][1]);                    \
        acc[1][0] = MFMA16(Areg[4*(Q_)+1], Xf[0], acc[1][0]);                    \
        acc[1][1] = MFMA16(Areg[4*(Q_)+1], Xf[1], acc[1][1]);                    \
        if (RDX) {                                                               \
            const char* _sx = ldsB + ((2*(Q_)+2) & 7) * 8192;                    \
            Xf[0] = *(const half8*)(_sx);                                        \
            Xf[1] = *(const half8*)(_sx + 1024);                                 \
        }                                                                        \
        acc[0][0] = MFMA16(Areg[4*(Q_)+2], Yf[0], acc[0][0]);                    \
        acc[0][1] = MFMA16(Areg[4*(Q_)+2], Yf[1], acc[0][1]);                    \
        acc[1][0] = MFMA16(Areg[4*(Q_)+3], Yf[0], acc[1][0]);                    \
        acc[1][1] = MFMA16(Areg[4*(Q_)+3], Yf[1], acc[1][1]);                    \
        __builtin_amdgcn_s_setprio(0);                                           \
    } while (0)

    for (int e0 = 0; e0 < 16; ++e0) {
        float wn0 = wn_ptr[0];
        float wn1 = wn_ptr[16];

        PBODY(0, "vmcnt(2)", 1, 0, 1);
        PBODY(1, "vmcnt(2)", 1, 0, 1);
        PBODY(2, "vmcnt(2)", 1, 0, 1);
        PBODY(3, "vmcnt(2)", 1, 0, 1);
        PBODY(4, "vmcnt(2)", 1, 0, 1);
        PBODY(5, "vmcnt(2)", 1, 0, 1);
        if (e0 < 15) {
            PBODY(6, "vmcnt(2)", 1, 1, 1);   // stages ks 0,1 of NEXT tile
            PBODY(7, "vmcnt(2)", 1, 1, 1);   // stages ks 2,3 of NEXT tile; X<-next ks0
        } else {
            PBODY(6, "vmcnt(2)", 0, 0, 1);
            PBODY(7, "vmcnt(0)", 0, 0, 0);
        }

        // fold: score = wnorm[e] - 2*dot; D: col=lane&15, row=(lane>>4)*4+reg
        {
            int colb = ebase + e0 * BN + wid * 32 + l15;
            #pragma unroll
            for (int ni = 0; ni < 2; ni++) {
                int col = colb + ni * 16;
                float wn = (ni == 0) ? wn0 : wn1;
                #pragma unroll
                for (int mi = 0; mi < 2; mi++)
                    #pragma unroll
                    for (int r = 0; r < 4; r++) {
                        float sc = fmaf(-2.0f, acc[mi][ni][r], wn);
                        int q = mi * 4 + r;
                        if (sc < v0[q])      { v1[q] = v0[q]; i1[q] = i0[q]; v0[q] = sc; i0[q] = col; }
                        else if (sc < v1[q]) { v1[q] = sc; i1[q] = col; }
                    }
            }
            #pragma unroll
            for (int mi = 0; mi < 2; mi++)
                #pragma unroll
                for (int ni = 0; ni < 2; ni++)
                    acc[mi][ni] = (f32x4){0.f, 0.f, 0.f, 0.f};
        }

        wn_ptr += BN;
        Bc0 += (size_t)BN * E_DIM;
        Bc1 += (size_t)BN * E_DIM;
    }
    #undef PBODY

    // merge buffer aliased into the slot region (B dead after main loop)
    __syncthreads();
    float4* SmTop = (float4*)Lds;   // [32 rows][4 waves]

    #pragma unroll
    for (int mi = 0; mi < 2; mi++)
        #pragma unroll
        for (int r = 0; r < 4; r++) {
            int q = mi * 4 + r;
            Top2 T = {v0[q], v1[q], i0[q], i1[q]};
            #pragma unroll
            for (int mk = 1; mk <= 8; mk <<= 1) {
                Top2 O;
                O.v0 = __shfl_xor(T.v0, mk); O.v1 = __shfl_xor(T.v1, mk);
                O.i0 = __shfl_xor(T.i0, mk); O.i1 = __shfl_xor(T.i1, mk);
                T = merge2(T, O);
            }
            if (l15 == 0) {
                int rl = mi * 16 + l4 * 4 + r;
                SmTop[rl * 4 + wid] = make_float4(T.v0, __int_as_float(T.i0), T.v1, __int_as_float(T.i1));
            }
        }
    __syncthreads();
    if (t < BM) {
        Top2 q[4];
        #pragma unroll
        for (int j = 0; j < 4; j++) {
            float4 F = SmTop[t * 4 + j];
            q[j].v0 = F.x; q[j].i0 = __float_as_int(F.y);
            q[j].v1 = F.z; q[j].i1 = __float_as_int(F.w);
        }
        Top2 T = merge2(merge2(q[0], q[1]), merge2(q[2], q[3]));
        cand[(size_t)(row0 + t) * (2 * NQ) + quarter * 2 + 0] = T.i0;
        cand[(size_t)(row0 + t) * (2 * NQ) + quarter * 2 + 1] = T.i1;
    }
}

// ---------------- fp32 rescore of 8 candidates + gather z_q + loss partial ----------------
__global__ __launch_bounds__(256) void rescore_gather_loss(
        const float* __restrict__ Z, const float* __restrict__ W,
        const float* __restrict__ wnorm, const int* __restrict__ cand,
        float* __restrict__ out, float* __restrict__ partials) {
    const int n = blockIdx.x;
    const int t = threadIdx.x;
    const int lane = t & 63, wv = t >> 6;
    int c[8];
    #pragma unroll
    for (int j = 0; j < 8; j++) c[j] = cand[(size_t)n * 8 + j];
    float2 zv = ((const float2*)(Z + (size_t)n * E_DIM))[t];
    float2 wvv[8];
    #pragma unroll
    for (int j = 0; j < 8; j++)
        wvv[j] = ((const float2*)(W + (size_t)c[j] * E_DIM))[t];
    __shared__ float red[4][8];
    #pragma unroll
    for (int j = 0; j < 8; j++) {
        float s = zv.x * wvv[j].x + zv.y * wvv[j].y;
        #pragma unroll
        for (int off = 32; off; off >>= 1) s += __shfl_down(s, off);
        if (lane == 0) red[wv][j] = s;
    }
    __syncthreads();
    float best = FLT_MAX; int bj = 0, bc = 0x7fffffff;
    #pragma unroll
    for (int j = 0; j < 8; j++) {
        float d = red[0][j] + red[1][j] + red[2][j] + red[3][j];
        float s = wnorm[c[j]] - 2.0f * d;
        if (s < best || (s == best && c[j] < bc)) { best = s; bj = j; bc = c[j]; }
    }
    float2 wq = wvv[0];                 // static-index select (rule #20)
    #pragma unroll
    for (int j = 1; j < 8; j++) if (bj == j) wq = wvv[j];
    ((float2*)(out + 1 + (size_t)n * E_DIM))[t] = wq;   // z_q_st == z_q numerically
    float d0 = wq.x - zv.x, d1 = wq.y - zv.y;
    float sl = d0 * d0 + d1 * d1;
    #pragma unroll
    for (int off = 32; off; off >>= 1) sl += __shfl_down(sl, off);
    __shared__ float red2[4];
    if (lane == 0) red2[wv] = sl;
    __syncthreads();
    if (t == 0) {
        partials[n] = red2[0] + red2[1] + red2[2] + red2[3];
        out[1 + (size_t)M_ROWS * E_DIM + n] = (float)bc;
    }
}

// ---------------- deterministic final loss reduction ----------------
__global__ __launch_bounds__(256) void loss_reduce_kernel(const float* __restrict__ partials,
                                                          float* __restrict__ out) {
    const int t = threadIdx.x;
    float s = 0.0f;
    for (int i = t; i < M_ROWS; i += 256) s += partials[i];
    #pragma unroll
    for (int off = 32; off; off >>= 1) s += __shfl_down(s, off);
    __shared__ float red[4];
    if ((t & 63) == 0) red[t >> 6] = s;
    __syncthreads();
    if (t == 0) {
        float total = red[0] + red[1] + red[2] + red[3];
        out[0] = 2.0f * total / ((float)M_ROWS * (float)E_DIM);  // beta=1 collapses
    }
}

extern "C" void kernel_launch(void* const* d_in, const int* in_sizes, int n_in,
                              void* d_out, int out_size, void* d_ws, size_t ws_size,
                              hipStream_t stream) {
    const float* Z = (const float*)d_in[0];
    const float* W = (const float*)d_in[1];
    float* out = (float*)d_out;

    char* p = (char*)d_ws;
    ushort* Zh = (ushort*)p;      p += (size_t)M_ROWS * E_DIM * 2;
    ushort* Wh = (ushort*)p;      p += (size_t)N_E * E_DIM * 2;
    float* wnorm = (float*)p;     p += (size_t)N_E * 4;
    int* cand = (int*)p;          p += (size_t)M_ROWS * 8 * 4;
    float* partials = (float*)p;  p += (size_t)M_ROWS * 4;

    f16_cast_kernel<<<(M_ROWS * E_DIM / 4 + 255) / 256, 256, 0, stream>>>(Z, Zh, M_ROWS * E_DIM / 4);
    f16_cast_kernel<<<(N_E * E_DIM / 4 + 255) / 256, 256, 0, stream>>>(W, Wh, N_E * E_DIM / 4);
    wnorm_kernel<<<N_E / 4, 256, 0, stream>>>(W, wnorm);
    argmin_mfma<<<NQ * (M_ROWS / BM), 256, 0, stream>>>(Zh, Wh, wnorm, cand);
    rescore_gather_loss<<<M_ROWS, 256, 0, stream>>>(Z, W, wnorm, cand, out, partials);
    loss_reduce_kernel<<<1, 256, 0, stream>>>(partials, out);
}